// Round 4
// baseline (402.558 us; speedup 1.0000x reference)
//
#include <hip/hip_runtime.h>
#include <hip/hip_fp16.h>
#include <cstdint>

#define GRAPHS 128

using half8 = __attribute__((ext_vector_type(8))) _Float16;
using f32x4 = __attribute__((ext_vector_type(4))) float;

__device__ __forceinline__ float lane_bcast_f(float v, int l) {
  return __int_as_float(__builtin_amdgcn_readlane(__float_as_int(v), l));
}
__device__ __forceinline__ void load_lds16(const __half* g, __half* l) {
  __builtin_amdgcn_global_load_lds(
      (const __attribute__((address_space(1))) void*)g,
      (__attribute__((address_space(3))) void*)l, 16, 0, 0);
}
#define WAIT_VM0 __builtin_amdgcn_s_waitcnt(0x0F70)  // vmcnt(0) only

// ---------------- prep A: degree histogram + weight transpose (merged, independent) ----------

__global__ __launch_bounds__(256) void k_degwt(
    const int* __restrict__ ei, int E, int ET, int* __restrict__ deg, int eb,
    const float* __restrict__ W1, __half* __restrict__ w1t,
    const float* __restrict__ W2, __half* __restrict__ w2t, int F, int HC, int LH) {
  int b = blockIdx.x;
  if (b < eb) {
    int e = b * 256 + threadIdx.x;
    if (e >= ET) return;
    int d = (e < E) ? ei[E + e] : (e - E);
    atomicAdd(&deg[d], 1);
    return;
  }
  int id = (b - eb) * 256 + threadIdx.x;
  if (id < F * HC) {
    int nn = id / F, kk = id % F;
    w1t[(size_t)nn * F + kk] = __float2half(W1[(size_t)kk * HC + nn]);
    return;
  }
  id -= F * HC;
  if (id < HC * LH) {
    int nn = id / HC, kk = id % HC;
    w2t[(size_t)nn * HC + kk] = __float2half(W2[(size_t)kk * LH + nn]);
  }
}

__global__ __launch_bounds__(256) void k_s1(const int* __restrict__ deg, int N,
                                            int* __restrict__ bsum) {
  int b = blockIdx.x, tid = threadIdx.x;
  int i0 = b * 1024 + tid * 4;
  int s = 0;
#pragma unroll
  for (int e = 0; e < 4; ++e) { int i = i0 + e; if (i < N) s += deg[i]; }
#pragma unroll
  for (int o = 32; o; o >>= 1) s += __shfl_xor(s, o);
  __shared__ int wt[4];
  int lane = tid & 63, wid = tid >> 6;
  if (lane == 0) wt[wid] = s;
  __syncthreads();
  if (tid == 0) bsum[b] = wt[0] + wt[1] + wt[2] + wt[3];
}

// s3: block prefix of bsum computed by a 64-lane parallel reduce (no serial chain)
__global__ __launch_bounds__(256) void k_s3(int* __restrict__ deg_cursor,
                                            const int* __restrict__ bsum, int N) {
  int b = blockIdx.x, tid = threadIdx.x;
  int lane = tid & 63, wid = tid >> 6;
  __shared__ int spre;
  if (tid < 64) {
    int run = 0;
    for (int base = 0; base < b; base += 64) {
      int idx = base + tid;
      int v = (idx < b) ? bsum[idx] : 0;
#pragma unroll
      for (int o = 32; o; o >>= 1) v += __shfl_xor(v, o);
      run += v;
    }
    if (tid == 0) spre = run;
  }
  int i0 = b * 1024 + tid * 4;
  int d[4];
#pragma unroll
  for (int e = 0; e < 4; ++e) { int i = i0 + e; d[e] = (i < N) ? deg_cursor[i] : 0; }
  int p0 = d[0], p1 = p0 + d[1], p2 = p1 + d[2], p3 = p2 + d[3];
  int incl = p3;
#pragma unroll
  for (int o = 1; o < 64; o <<= 1) { int u = __shfl_up(incl, o); if (lane >= o) incl += u; }
  __shared__ int wt[4];
  if (lane == 63) wt[wid] = incl;
  __syncthreads();
  int woff = 0;
  for (int w = 0; w < wid; ++w) woff += wt[w];
  int ex = spre + woff + incl - p3;
  int pre[4] = {0, p0, p1, p2};
#pragma unroll
  for (int e = 0; e < 4; ++e) {
    int i = i0 + e;
    if (i < N) deg_cursor[i] = ex + pre[e];
  }
}

// scatter: only SRC is stored (dst is derivable from rowptr in the node-parallel agg).
// 4B random store per edge (halved write-allocate traffic vs int2).
__global__ __launch_bounds__(256) void k_scatter(const int* __restrict__ ei, int E, int ET,
                                                 int* __restrict__ cursor,
                                                 int* __restrict__ csrs) {
  int e = blockIdx.x * 256 + threadIdx.x;
  if (e >= ET) return;
  int s, d;
  if (e < E) { s = ei[e]; d = ei[E + e]; } else { s = d = e - E; }
  int pos = atomicAdd(&cursor[d], 1);
  csrs[pos] = s;
}

// ---------------- MFMA GEMM, LDS-tiled, fp32 A staged ONCE, NH head-blocks looped -----------
// MODE 0: A = raw fp32 (x).
// MODE 1: A = unnormalized numerators (h1f) -> /denom + bias + ELU during staging.

template <int KT, int ASTR, int NH, int MODE>
__global__ __launch_bounds__(256) void k_gemm_mfma(
    const float* __restrict__ Af, const __half* __restrict__ Bth,
    __half* __restrict__ C, const float* __restrict__ attS, const float* __restrict__ attD,
    float* __restrict__ aS, float* __restrict__ aD, const float* __restrict__ bias,
    const float* __restrict__ dnm, int Ndn, int M, int NC) {
  constexpr int K8 = KT / 8;
  constexpr int KS = KT / 32;
  __shared__ __align__(16) _Float16 Asm[64 * KT];
  __shared__ __align__(16) _Float16 Csm[64 * 64];
  __shared__ float sS[64][4], sD[64][4];
  int tid = threadIdx.x;
  int w = tid >> 6, lane = tid & 63;
  int col = lane & 15, quad = lane >> 4;
  int m0 = blockIdx.x * 64;
  half8* As8 = (half8*)Asm;
  for (int i = tid; i < 64 * K8; i += 256) {
    int row = i / K8, c8 = i % K8;
    int gm = min(m0 + row, M - 1);
    const float* src = Af + (size_t)gm * KT + c8 * 8;
    float4 v0 = *(const float4*)src;
    float4 v1 = *(const float4*)(src + 4);
    float o[8] = {v0.x, v0.y, v0.z, v0.w, v1.x, v1.y, v1.z, v1.w};
    if (MODE == 1) {
      int c = c8 * 8;
      float inv = 1.0f / fmaxf(dnm[(size_t)(c8 >> 3) * Ndn + gm], 1e-16f);
#pragma unroll
      for (int k = 0; k < 8; ++k) {
        float t = o[k] * inv + bias[c + k];
        o[k] = t > 0.f ? t : __expf(t) - 1.f;
      }
    }
    half8 h;
#pragma unroll
    for (int k = 0; k < 8; ++k) h[k] = (_Float16)o[k];
    As8[i] = h;
  }
  __syncthreads();
  const half8* B8 = (const half8*)Bth;
  for (int h = 0; h < NH; ++h) {
    int nblk = h * 64;
    int n0w = nblk + w * 16;
    half8 bf[KS];
#pragma unroll
    for (int s = 0; s < KS; ++s) bf[s] = B8[(size_t)(n0w + col) * K8 + s * 4 + quad];
    float asv = attS[n0w + col], adv = attD[n0w + col];
    if (h) __syncthreads();  // prev head's sS/sD consumed + Csm flushed
    f32x4 accs[4];
#pragma unroll
    for (int i = 0; i < 4; ++i) {
      f32x4 acc = {0.f, 0.f, 0.f, 0.f};
#pragma unroll
      for (int s = 0; s < KS; ++s) {
        half8 a = *(const half8*)&Asm[(i * 16 + col) * KT + s * 32 + quad * 8];
        acc = __builtin_amdgcn_mfma_f32_16x16x32_f16(a, bf[s], acc, 0, 0, 0);
      }
      accs[i] = acc;
#pragma unroll
      for (int r = 0; r < 4; ++r) {
        float sv = acc[r] * asv, dv = acc[r] * adv;
#pragma unroll
        for (int o = 1; o < 16; o <<= 1) { sv += __shfl_xor(sv, o); dv += __shfl_xor(dv, o); }
        if (col == 0) {
          int ml = i * 16 + quad * 4 + r;
          sS[ml][w] = sv; sD[ml][w] = dv;
        }
      }
    }
    __syncthreads();
    if (tid < 64) {
      int m = m0 + tid;
      if (m < M) {
        aS[(size_t)m * ASTR + h] = sS[tid][0] + sS[tid][1] + sS[tid][2] + sS[tid][3];
        aD[(size_t)m * ASTR + h] = sD[tid][0] + sD[tid][1] + sD[tid][2] + sD[tid][3];
      }
    }
#pragma unroll
    for (int i = 0; i < 4; ++i)
#pragma unroll
      for (int r = 0; r < 4; ++r)
        Csm[(i * 16 + quad * 4 + r) * 64 + w * 16 + col] = (_Float16)accs[i][r];
    __syncthreads();
    for (int i = tid; i < 64 * 8; i += 256) {
      int row = i >> 3, c8 = i & 7;
      int gm = m0 + row;
      if (gm < M)
        *(half8*)&C[(size_t)gm * NC + nblk + c8 * 8] = ((half8*)Csm)[row * 8 + c8];
    }
  }
}

// ---------------- NODE-parallel aggregation, V=3 nodes/wave, ZERO atomics ----------------
// dst-sorted edge groups == nodes 0..N-1 in order; cursor (post-scatter) == group ENDS.
// Each wave owns nodes [3*wv, 3*wv+3): edge range [b, e) from rowptr, processed in <=64-edge
// passes. dst is DERIVED (no dst array); flush boundaries are wave-uniform integer compares;
// every output row / denom is written exactly once with a PLAIN store -> no memset of h1f/
// h2f/dnm, no atomic RMW anywhere.

template <int NH>
__global__ __launch_bounds__(256) void k_aggE(
    const int* __restrict__ csrs,
    const float* __restrict__ aS, const float* __restrict__ aD,
    const __half* __restrict__ xp, float* __restrict__ outf, float* __restrict__ dnm,
    const int* __restrict__ gend,  // cursor post-scatter: gend[d] = end of group d
    int ET, int N, int rowstr, int ostr, int Ndn) {
  __shared__ __half stage[4][4096];
  int wv = (blockIdx.x * 256 + (int)threadIdx.x) >> 6;
  int lane = threadIdx.x & 63;
  int wid = (threadIdx.x >> 6) & 3;
  __half* st = stage[wid];
  int head = blockIdx.y;
  int coloff = head * 64;
  int n0 = wv * 3;
  if (n0 >= N) return;
  // group bounds (wave-uniform scalar loads)
  int b = (n0 == 0) ? 0 : gend[n0 - 1];
  int e0 = gend[n0];
  int e1 = (n0 + 1 < N) ? gend[n0 + 1] : e0;
  int e2 = (n0 + 2 < N) ? gend[n0 + 2] : e1;
  int e = e2;
  // per-node attn-dst values (uniform scalar loads, replaces per-lane gather)
  float d0, d1, d2;
  if (NH == 3) {
    d0 = aD[(size_t)n0 * 4 + head];
    d1 = (n0 + 1 < N) ? aD[(size_t)(n0 + 1) * 4 + head] : 0.f;
    d2 = (n0 + 2 < N) ? aD[(size_t)(n0 + 2) * 4 + head] : 0.f;
  } else {
    d0 = aD[n0];
    d1 = (n0 + 1 < N) ? aD[n0 + 1] : 0.f;
    d2 = (n0 + 2 < N) ? aD[n0 + 2] : 0.f;
  }
  float acc = 0.f, dsum = 0.f;
  int ncur = n0, nend = e0;
  int base = b;
  while (true) {
    int rem = min(64, e - base);
    int j = base + lane;
    int jc = min(j, e - 1);
    int sreg = csrs[jc];                       // coalesced 4B
    // alpha (issued before DMAs; the single vmcnt(0) covers everything)
    float dv = (j < e0) ? d0 : ((j < e1) ? d1 : d2);
    float sv;
    if (NH == 3) {
      float4 a4 = *(const float4*)&aS[(size_t)sreg * 4];  // random 16B, L2-resident
      sv = (head == 0) ? a4.x : ((head == 1) ? a4.y : a4.z);
    } else {
      sv = aS[sreg];
    }
    float v = sv + dv;
    v = v > 0.f ? v : 0.2f * v;
    float dd = __expf(v);
    int nk = (rem + 7) >> 3;                   // DMAs actually needed this pass
    for (int k = 0; k < nk; ++k) {
      int src = __shfl(sreg, k * 8 + (lane >> 3));
      const __half* g = xp + (size_t)src * rowstr + coloff + (lane & 7) * 8;
      load_lds16(g, st + k * 512);             // 8 rows of 64 halves per DMA
    }
    WAIT_VM0;
#pragma unroll 4
    for (int u = 0; u < rem; ++u) {
      float c = lane_bcast_f(dd, u);
      acc = fmaf(c, __half2float(st[(u >> 3) * 512 + (u & 7) * 64 + lane]), acc);
      dsum += c;
      int ej = base + u;
      if (ej == nend - 1) {                    // wave-uniform: node ncur's group ends here
        outf[(size_t)ncur * ostr + coloff + lane] = acc;   // PLAIN store, exactly once
        if (lane == 0) dnm[(size_t)head * Ndn + ncur] = dsum;
        acc = 0.f; dsum = 0.f;
        ++ncur;
        nend = (ncur == n0 + 1) ? e1 : e2;
      }
    }
    base += 64;
    if (base >= e) break;
    __builtin_amdgcn_sched_barrier(0);         // keep next-pass DMA issue after LDS reads
  }
}

// ---------------- fused pooling + final linear (one block per graph, NO atomics) ------------

__global__ __launch_bounds__(256) void k_poolfinal(
    const float* __restrict__ h2f, const float* __restrict__ dnm2,
    const int* __restrict__ batch, const float* __restrict__ b2,
    const float* __restrict__ lw, const float* __restrict__ lb,
    float* __restrict__ out, int N) {
  int g = blockIdx.x;
  __shared__ int sse[2];
  __shared__ float red[4][64];
  if (threadIdx.x < 2) {
    int target = g + (int)threadIdx.x;
    int lo = 0, hi = N;
    while (lo < hi) { int mid = (lo + hi) >> 1; if (batch[mid] < target) lo = mid + 1; else hi = mid; }
    sse[threadIdx.x] = lo;
  }
  __syncthreads();
  int start = sse[0], end = sse[1];
  int lane = threadIdx.x & 63, wid = threadIdx.x >> 6;
  float acc = 0.f;
  for (int n = start + wid; n < end; n += 4) {
    float inv = 1.0f / fmaxf(dnm2[n], 1e-16f);
    acc = fmaf(h2f[(size_t)n * 64 + lane], inv, acc);
  }
  red[wid][lane] = acc;
  __syncthreads();
  if (wid == 0) {
    float inv = 1.0f / fmaxf((float)(end - start), 1.0f);
    float pv = (red[0][lane] + red[1][lane] + red[2][lane] + red[3][lane]) * inv + b2[lane];
#pragma unroll
    for (int k = 0; k < 10; ++k) {
      float v = pv * lw[lane * 10 + k];
#pragma unroll
      for (int o = 1; o < 64; o <<= 1) v += __shfl_xor(v, o);
      if (lane == 0) out[g * 10 + k] = v + lb[k];
    }
  }
}

extern "C" void kernel_launch(void* const* d_in, const int* in_sizes, int n_in,
                              void* d_out, int out_size, void* d_ws, size_t ws_size,
                              hipStream_t stream) {
  const float* x = (const float*)d_in[0];
  const int* ei = (const int*)d_in[1];
  const int* batch = (const int*)d_in[2];
  const float* W1 = (const float*)d_in[3];
  const float* as1 = (const float*)d_in[4];
  const float* ad1 = (const float*)d_in[5];
  const float* b1 = (const float*)d_in[6];
  const float* W2 = (const float*)d_in[7];
  const float* as2 = (const float*)d_in[8];
  const float* ad2 = (const float*)d_in[9];
  const float* b2 = (const float*)d_in[10];
  const float* lw = (const float*)d_in[11];
  const float* lb = (const float*)d_in[12];
  float* out = (float*)d_out;

  const int N = in_sizes[2];        // 50000
  const int E = in_sizes[1] / 2;    // 800000
  const int ET = E + N;             // + self loops
  const int F = in_sizes[0] / N;    // 128
  const int HC = in_sizes[6];       // 192
  const int LH = in_sizes[10];      // 64

  size_t off = 0;
  auto alo = [&](size_t bytes) -> char* {
    char* p = (char*)d_ws + off;
    off += (bytes + 255) & ~(size_t)255;
    return p;
  };
  int* cursor = (int*)alo((size_t)N * 4);           // ONLY zeroed region
  size_t zbytes = off;
  float* h1f = (float*)alo((size_t)N * 192 * 4);    // fp32 numerators (fully written)
  float* h2f = (float*)alo((size_t)N * 64 * 4);
  float* dnm1 = (float*)alo((size_t)3 * N * 4);     // softmax denominators [head][node]
  float* dnm2 = (float*)alo((size_t)N * 4);
  float* aS1 = (float*)alo((size_t)N * 4 * 4);      // direct-stored by GEMM
  float* aD1 = (float*)alo((size_t)N * 4 * 4);
  float* aS2 = (float*)alo((size_t)N * 4);
  float* aD2 = (float*)alo((size_t)N * 4);
  int* csrs = (int*)alo((size_t)ET * 4);            // src per edge, dst-sorted (CSR)
  int* bsum = (int*)alo(64 * 4);
  __half* w1t = (__half*)alo((size_t)HC * F * 2);
  __half* w2t = (__half*)alo((size_t)LH * HC * 2);
  __half* xp1 = (__half*)alo((size_t)N * 192 * 2 + 512);  // +pad: DMA clamp overreach
  __half* xp2 = (__half*)alo((size_t)N * 64 * 2 + 512);

  hipMemsetAsync(d_ws, 0, zbytes, stream);          // 200KB, was 52MB
  int eb = (ET + 255) / 256;
  int wtTot = F * HC + HC * LH;
  int wtb = (wtTot + 255) / 256;
  k_degwt<<<eb + wtb, 256, 0, stream>>>(ei, E, ET, cursor, eb, W1, w1t, W2, w2t, F, HC, LH);
  int nb = (N + 1023) / 1024;
  k_s1<<<nb, 256, 0, stream>>>(cursor, N, bsum);
  k_s3<<<nb, 256, 0, stream>>>(cursor, bsum, N);
  k_scatter<<<eb, 256, 0, stream>>>(ei, E, ET, cursor, csrs);
  // cursor is now gend[d] = rowptr[d+1]

  int mb = (N + 63) / 64;
  int waves3 = (N + 2) / 3;         // V=3 nodes per wave
  int ebk = (waves3 + 3) / 4;

  // ---- layer 1: MFMA GEMM (A staged once, 3 head-blocks looped) -> node-parallel agg ----
  k_gemm_mfma<128, 4, 3, 0><<<mb, 256, 0, stream>>>(x, w1t, xp1, as1, ad1, aS1, aD1,
                                                    nullptr, nullptr, 0, N, HC);
  dim3 ge1(ebk, 3);
  k_aggE<3><<<ge1, 256, 0, stream>>>(csrs, aS1, aD1, xp1, h1f, dnm1, cursor,
                                     ET, N, 192, 192, N);
  // ---- layer 2: MFMA GEMM (A = h1f/denom + bias + ELU) -> agg -> pool+final ----
  k_gemm_mfma<192, 1, 1, 1><<<mb, 256, 0, stream>>>(h1f, w2t, xp2, as2, ad2, aS2, aD2,
                                                    b1, dnm1, N, N, LH);
  dim3 ge2(ebk, 1);
  k_aggE<1><<<ge2, 256, 0, stream>>>(csrs, aS2, aD2, xp2, h2f, dnm2, cursor,
                                     ET, N, 64, 64, N);
  k_poolfinal<<<GRAPHS, 256, 0, stream>>>(h2f, dnm2, batch, b2, lw, lb, out, N);
}

// Round 5
// 396.106 us; speedup vs baseline: 1.0163x; 1.0163x over previous
//
#include <hip/hip_runtime.h>
#include <hip/hip_fp16.h>
#include <cstdint>

#define GRAPHS 128

using half8 = __attribute__((ext_vector_type(8))) _Float16;
using f32x4 = __attribute__((ext_vector_type(4))) float;

__device__ __forceinline__ int lane_bcast_i(int v, int l) {
  return __builtin_amdgcn_readlane(v, l);
}
__device__ __forceinline__ float lane_bcast_f(float v, int l) {
  return __int_as_float(__builtin_amdgcn_readlane(__float_as_int(v), l));
}
__device__ __forceinline__ void load_lds16(const __half* g, __half* l) {
  __builtin_amdgcn_global_load_lds(
      (const __attribute__((address_space(1))) void*)g,
      (__attribute__((address_space(3))) void*)l, 16, 0, 0);
}
#define WAIT_VM0 __builtin_amdgcn_s_waitcnt(0x0F70)  // vmcnt(0) only

// ---------------- prep A: degree histogram + weight transpose (merged, independent) ----------

__global__ __launch_bounds__(256) void k_degwt(
    const int* __restrict__ ei, int E, int ET, int* __restrict__ deg, int eb,
    const float* __restrict__ W1, __half* __restrict__ w1t,
    const float* __restrict__ W2, __half* __restrict__ w2t, int F, int HC, int LH) {
  int b = blockIdx.x;
  if (b < eb) {
    int e = b * 256 + threadIdx.x;
    if (e >= ET) return;
    int d = (e < E) ? ei[E + e] : (e - E);
    atomicAdd(&deg[d], 1);
    return;
  }
  int id = (b - eb) * 256 + threadIdx.x;
  if (id < F * HC) {
    int nn = id / F, kk = id % F;
    w1t[(size_t)nn * F + kk] = __float2half(W1[(size_t)kk * HC + nn]);
    return;
  }
  id -= F * HC;
  if (id < HC * LH) {
    int nn = id / HC, kk = id % HC;
    w2t[(size_t)nn * HC + kk] = __float2half(W2[(size_t)kk * LH + nn]);
  }
}

__global__ __launch_bounds__(256) void k_s1(const int* __restrict__ deg, int N,
                                            int* __restrict__ bsum) {
  int b = blockIdx.x, tid = threadIdx.x;
  int i0 = b * 1024 + tid * 4;
  int s = 0;
#pragma unroll
  for (int e = 0; e < 4; ++e) { int i = i0 + e; if (i < N) s += deg[i]; }
#pragma unroll
  for (int o = 32; o; o >>= 1) s += __shfl_xor(s, o);
  __shared__ int wt[4];
  int lane = tid & 63, wid = tid >> 6;
  if (lane == 0) wt[wid] = s;
  __syncthreads();
  if (tid == 0) bsum[b] = wt[0] + wt[1] + wt[2] + wt[3];
}

// s3: block prefix of bsum computed by a 64-lane parallel reduce (no serial chain)
__global__ __launch_bounds__(256) void k_s3(int* __restrict__ deg_cursor,
                                            const int* __restrict__ bsum, int N) {
  int b = blockIdx.x, tid = threadIdx.x;
  int lane = tid & 63, wid = tid >> 6;
  __shared__ int spre;
  if (tid < 64) {
    int run = 0;
    for (int base = 0; base < b; base += 64) {
      int idx = base + tid;
      int v = (idx < b) ? bsum[idx] : 0;
#pragma unroll
      for (int o = 32; o; o >>= 1) v += __shfl_xor(v, o);
      run += v;
    }
    if (tid == 0) spre = run;
  }
  int i0 = b * 1024 + tid * 4;
  int d[4];
#pragma unroll
  for (int e = 0; e < 4; ++e) { int i = i0 + e; d[e] = (i < N) ? deg_cursor[i] : 0; }
  int p0 = d[0], p1 = p0 + d[1], p2 = p1 + d[2], p3 = p2 + d[3];
  int incl = p3;
#pragma unroll
  for (int o = 1; o < 64; o <<= 1) { int u = __shfl_up(incl, o); if (lane >= o) incl += u; }
  __shared__ int wt[4];
  if (lane == 63) wt[wid] = incl;
  __syncthreads();
  int woff = 0;
  for (int w = 0; w < wid; ++w) woff += wt[w];
  int ex = spre + woff + incl - p3;
  int pre[4] = {0, p0, p1, p2};
#pragma unroll
  for (int e = 0; e < 4; ++e) {
    int i = i0 + e;
    if (i < N) deg_cursor[i] = ex + pre[e];
  }
}

// packed (src,dst) scatter: ONE random 8B store per edge instead of two 4B
__global__ __launch_bounds__(256) void k_scatter(const int* __restrict__ ei, int E, int ET,
                                                 int* __restrict__ cursor,
                                                 int2* __restrict__ epk) {
  int e = blockIdx.x * 256 + threadIdx.x;
  if (e >= ET) return;
  int s, d;
  if (e < E) { s = ei[e]; d = ei[E + e]; } else { s = d = e - E; }
  int pos = atomicAdd(&cursor[d], 1);
  epk[pos] = make_int2(s, d);
}

// ---------------- MFMA GEMM, LDS-tiled, fp32 A staged ONCE, NH head-blocks looped -----------
// MODE 0: A = raw fp32 (x).
// MODE 1: A = unnormalized numerators (h1f) -> /denom + bias + ELU during staging.

template <int KT, int ASTR, int NH, int MODE>
__global__ __launch_bounds__(256) void k_gemm_mfma(
    const float* __restrict__ Af, const __half* __restrict__ Bth,
    __half* __restrict__ C, const float* __restrict__ attS, const float* __restrict__ attD,
    float* __restrict__ aS, float* __restrict__ aD, const float* __restrict__ bias,
    const float* __restrict__ dnm, int Ndn, int M, int NC) {
  constexpr int K8 = KT / 8;
  constexpr int KS = KT / 32;
  __shared__ __align__(16) _Float16 Asm[64 * KT];
  __shared__ __align__(16) _Float16 Csm[64 * 64];
  __shared__ float sS[64][4], sD[64][4];
  int tid = threadIdx.x;
  int w = tid >> 6, lane = tid & 63;
  int col = lane & 15, quad = lane >> 4;
  int m0 = blockIdx.x * 64;
  half8* As8 = (half8*)Asm;
  for (int i = tid; i < 64 * K8; i += 256) {
    int row = i / K8, c8 = i % K8;
    int gm = min(m0 + row, M - 1);
    const float* src = Af + (size_t)gm * KT + c8 * 8;
    float4 v0 = *(const float4*)src;
    float4 v1 = *(const float4*)(src + 4);
    float o[8] = {v0.x, v0.y, v0.z, v0.w, v1.x, v1.y, v1.z, v1.w};
    if (MODE == 1) {
      int c = c8 * 8;
      float inv = 1.0f / fmaxf(dnm[(size_t)(c8 >> 3) * Ndn + gm], 1e-16f);
#pragma unroll
      for (int k = 0; k < 8; ++k) {
        float t = o[k] * inv + bias[c + k];
        o[k] = t > 0.f ? t : __expf(t) - 1.f;
      }
    }
    half8 h;
#pragma unroll
    for (int k = 0; k < 8; ++k) h[k] = (_Float16)o[k];
    As8[i] = h;
  }
  __syncthreads();
  const half8* B8 = (const half8*)Bth;
  for (int h = 0; h < NH; ++h) {
    int nblk = h * 64;
    int n0w = nblk + w * 16;
    half8 bf[KS];
#pragma unroll
    for (int s = 0; s < KS; ++s) bf[s] = B8[(size_t)(n0w + col) * K8 + s * 4 + quad];
    float asv = attS[n0w + col], adv = attD[n0w + col];
    if (h) __syncthreads();  // prev head's sS/sD consumed + Csm flushed
    f32x4 accs[4];
#pragma unroll
    for (int i = 0; i < 4; ++i) {
      f32x4 acc = {0.f, 0.f, 0.f, 0.f};
#pragma unroll
      for (int s = 0; s < KS; ++s) {
        half8 a = *(const half8*)&Asm[(i * 16 + col) * KT + s * 32 + quad * 8];
        acc = __builtin_amdgcn_mfma_f32_16x16x32_f16(a, bf[s], acc, 0, 0, 0);
      }
      accs[i] = acc;
#pragma unroll
      for (int r = 0; r < 4; ++r) {
        float sv = acc[r] * asv, dv = acc[r] * adv;
#pragma unroll
        for (int o = 1; o < 16; o <<= 1) { sv += __shfl_xor(sv, o); dv += __shfl_xor(dv, o); }
        if (col == 0) {
          int ml = i * 16 + quad * 4 + r;
          sS[ml][w] = sv; sD[ml][w] = dv;
        }
      }
    }
    __syncthreads();
    if (tid < 64) {
      int m = m0 + tid;
      if (m < M) {
        aS[(size_t)m * ASTR + h] = sS[tid][0] + sS[tid][1] + sS[tid][2] + sS[tid][3];
        aD[(size_t)m * ASTR + h] = sD[tid][0] + sD[tid][1] + sD[tid][2] + sD[tid][3];
      }
    }
#pragma unroll
    for (int i = 0; i < 4; ++i)
#pragma unroll
      for (int r = 0; r < 4; ++r)
        Csm[(i * 16 + quad * 4 + r) * 64 + w * 16 + col] = (_Float16)accs[i][r];
    __syncthreads();
    for (int i = tid; i < 64 * 8; i += 256) {
      int row = i >> 3, c8 = i & 7;
      int gm = m0 + row;
      if (gm < M)
        *(half8*)&C[(size_t)gm * NC + nblk + c8 * 8] = ((half8*)Csm)[row * 8 + c8];
    }
  }
}

// ---------------- edge-parallel aggregation, 64-edge chunks, interior plain stores ----------
// One chunk per wave, single vmcnt(0) covering alpha gathers + 8 staging DMAs.
// head is a kernel ARGUMENT (per-head dispatch) so each head's duration/counters are
// individually visible in the profile.

template <int NH>
__global__ __launch_bounds__(256) void k_aggE(
    const int2* __restrict__ ep,
    const float* __restrict__ aS, const float* __restrict__ aD,
    const __half* __restrict__ xp, float* __restrict__ outf, float* __restrict__ dnm,
    int ET, int rowstr, int ostr, int Ndn, int head) {
  __shared__ __half stage[4][4096];
  int wv = (blockIdx.x * 256 + (int)threadIdx.x) >> 6;
  int lane = threadIdx.x & 63;
  int wid = (threadIdx.x >> 6) & 3;
  __half* st = stage[wid];
  int coloff = head * 64;
  int e0 = wv * 64;
  if (e0 >= ET) return;
  int j = e0 + lane;
  int jc = min(j, ET - 1);
  int2 sd = ep[jc];                            // coalesced 8B
  int sreg = sd.x, dstv = sd.y;
  // inline alpha: issued before DMAs; same vmcnt(0) covers everything
  float dd = 0.f;
  if (NH == 3) {
    float4 a4 = *(const float4*)&aS[(size_t)sreg * 4];   // random 16B, L2-resident
    float4 b4 = *(const float4*)&aD[(size_t)dstv * 4];   // dst-sorted -> near-coalesced
    float v = (head == 0) ? (a4.x + b4.x) : ((head == 1) ? (a4.y + b4.y) : (a4.z + b4.z));
    v = v > 0.f ? v : 0.2f * v;
    dd = __expf(v);
  } else {
    float v = aS[sreg] + aD[dstv];
    v = v > 0.f ? v : 0.2f * v;
    dd = __expf(v);
  }
  if (j >= ET) dd = 0.f;
#pragma unroll
  for (int k = 0; k < 8; ++k) {
    int src = __shfl(sreg, k * 8 + (lane >> 3));
    const __half* g = xp + (size_t)src * rowstr + coloff + (lane & 7) * 8;
    load_lds16(g, st + k * 512);               // 8 rows of 64 halves per DMA
  }
  int dn = __shfl_down(dstv, 1);
  unsigned long long bmask = __ballot(lane == 63 || dn != dstv);  // segment-end lanes
  WAIT_VM0;                                    // the only wait in the wave's lifetime
  float acc = 0.f, dsum = 0.f;
  int dcur = lane_bcast_i(dstv, 0);
  int segstart = 0;
#pragma unroll 4
  for (int u = 0; u < 64; ++u) {
    float c = lane_bcast_f(dd, u);
    acc = fmaf(c, __half2float(st[(u >> 3) * 512 + (u & 7) * 64 + lane]), acc);
    dsum += c;
    if ((bmask >> u) & 1ull) {                 // wave-uniform scalar test
      size_t op = (size_t)dcur * ostr + coloff + lane;
      if (segstart > 0 && u < 63) {            // complete segment: plain store
        outf[op] = acc;
        if (lane == 0) dnm[(size_t)head * Ndn + dcur] = dsum;
      } else {                                 // chunk-boundary segment: atomic
        atomicAdd(&outf[op], acc);
        if (lane == 0) atomicAdd(&dnm[(size_t)head * Ndn + dcur], dsum);
      }
      acc = 0.f; dsum = 0.f; segstart = u + 1;
      if (u < 63) dcur = lane_bcast_i(dstv, u + 1);
    }
  }
}

// ---------------- fused pooling + final linear (one block per graph, NO atomics) ------------

__global__ __launch_bounds__(256) void k_poolfinal(
    const float* __restrict__ h2f, const float* __restrict__ dnm2,
    const int* __restrict__ batch, const float* __restrict__ b2,
    const float* __restrict__ lw, const float* __restrict__ lb,
    float* __restrict__ out, int N) {
  int g = blockIdx.x;
  __shared__ int sse[2];
  __shared__ float red[4][64];
  if (threadIdx.x < 2) {
    int target = g + (int)threadIdx.x;
    int lo = 0, hi = N;
    while (lo < hi) { int mid = (lo + hi) >> 1; if (batch[mid] < target) lo = mid + 1; else hi = mid; }
    sse[threadIdx.x] = lo;
  }
  __syncthreads();
  int start = sse[0], end = sse[1];
  int lane = threadIdx.x & 63, wid = threadIdx.x >> 6;
  float acc = 0.f;
  for (int n = start + wid; n < end; n += 4) {
    float inv = 1.0f / fmaxf(dnm2[n], 1e-16f);
    acc = fmaf(h2f[(size_t)n * 64 + lane], inv, acc);
  }
  red[wid][lane] = acc;
  __syncthreads();
  if (wid == 0) {
    float inv = 1.0f / fmaxf((float)(end - start), 1.0f);
    float pv = (red[0][lane] + red[1][lane] + red[2][lane] + red[3][lane]) * inv + b2[lane];
#pragma unroll
    for (int k = 0; k < 10; ++k) {
      float v = pv * lw[lane * 10 + k];
#pragma unroll
      for (int o = 1; o < 64; o <<= 1) v += __shfl_xor(v, o);
      if (lane == 0) out[g * 10 + k] = v + lb[k];
    }
  }
}

extern "C" void kernel_launch(void* const* d_in, const int* in_sizes, int n_in,
                              void* d_out, int out_size, void* d_ws, size_t ws_size,
                              hipStream_t stream) {
  const float* x = (const float*)d_in[0];
  const int* ei = (const int*)d_in[1];
  const int* batch = (const int*)d_in[2];
  const float* W1 = (const float*)d_in[3];
  const float* as1 = (const float*)d_in[4];
  const float* ad1 = (const float*)d_in[5];
  const float* b1 = (const float*)d_in[6];
  const float* W2 = (const float*)d_in[7];
  const float* as2 = (const float*)d_in[8];
  const float* ad2 = (const float*)d_in[9];
  const float* b2 = (const float*)d_in[10];
  const float* lw = (const float*)d_in[11];
  const float* lb = (const float*)d_in[12];
  float* out = (float*)d_out;

  const int N = in_sizes[2];        // 50000
  const int E = in_sizes[1] / 2;    // 800000
  const int ET = E + N;             // + self loops
  const int F = in_sizes[0] / N;    // 128
  const int HC = in_sizes[6];       // 192
  const int LH = in_sizes[10];      // 64

  size_t off = 0;
  auto alo = [&](size_t bytes) -> char* {
    char* p = (char*)d_ws + off;
    off += (bytes + 255) & ~(size_t)255;
    return p;
  };
  int* cursor = (int*)alo((size_t)N * 4);
  float* h1f = (float*)alo((size_t)N * 192 * 4);    // fp32 unnormalized numerators
  float* h2f = (float*)alo((size_t)N * 64 * 4);
  float* dnm1 = (float*)alo((size_t)3 * N * 4);     // softmax denominators [head][node]
  float* dnm2 = (float*)alo((size_t)N * 4);
  size_t zbytes = off;                              // zero everything above
  float* aS1 = (float*)alo((size_t)N * 4 * 4);      // direct-stored by GEMM
  float* aD1 = (float*)alo((size_t)N * 4 * 4);
  float* aS2 = (float*)alo((size_t)N * 4);
  float* aD2 = (float*)alo((size_t)N * 4);
  int2* epk = (int2*)alo((size_t)ET * 8);           // packed (src,dst), CSR-sorted
  int* bsum = (int*)alo(64 * 4);
  __half* w1t = (__half*)alo((size_t)HC * F * 2);
  __half* w2t = (__half*)alo((size_t)LH * HC * 2);
  __half* xp1 = (__half*)alo((size_t)N * 192 * 2 + 512);  // +pad: DMA clamp overreach
  __half* xp2 = (__half*)alo((size_t)N * 64 * 2 + 512);

  hipMemsetAsync(d_ws, 0, zbytes, stream);
  int eb = (ET + 255) / 256;
  int wtTot = F * HC + HC * LH;
  int wtb = (wtTot + 255) / 256;
  k_degwt<<<eb + wtb, 256, 0, stream>>>(ei, E, ET, cursor, eb, W1, w1t, W2, w2t, F, HC, LH);
  int nb = (N + 1023) / 1024;
  k_s1<<<nb, 256, 0, stream>>>(cursor, N, bsum);
  k_s3<<<nb, 256, 0, stream>>>(cursor, bsum, N);
  k_scatter<<<eb, 256, 0, stream>>>(ei, E, ET, cursor, epk);

  int mb = (N + 63) / 64;
  int wavesE = (ET + 63) / 64;
  int ebk = (wavesE + 3) / 4;

  // ---- layer 1: MFMA GEMM (A staged once, 3 head-blocks looped) -> per-head agg dispatches ----
  k_gemm_mfma<128, 4, 3, 0><<<mb, 256, 0, stream>>>(x, w1t, xp1, as1, ad1, aS1, aD1,
                                                    nullptr, nullptr, 0, N, HC);
  k_aggE<3><<<ebk, 256, 0, stream>>>(epk, aS1, aD1, xp1, h1f, dnm1, ET, 192, 192, N, 0);
  k_aggE<3><<<ebk, 256, 0, stream>>>(epk, aS1, aD1, xp1, h1f, dnm1, ET, 192, 192, N, 1);
  k_aggE<3><<<ebk, 256, 0, stream>>>(epk, aS1, aD1, xp1, h1f, dnm1, ET, 192, 192, N, 2);
  // ---- layer 2: MFMA GEMM (A = h1f/denom + bias + ELU) -> agg -> pool+final ----
  k_gemm_mfma<192, 1, 1, 1><<<mb, 256, 0, stream>>>(h1f, w2t, xp2, as2, ad2, aS2, aD2,
                                                    b1, dnm1, N, N, LH);
  k_aggE<1><<<ebk, 256, 0, stream>>>(epk, aS2, aD2, xp2, h2f, dnm2, ET, 64, 64, N, 0);
  k_poolfinal<<<GRAPHS, 256, 0, stream>>>(h2f, dnm2, batch, b2, lw, lb, out, N);
}

// Round 6
// 317.617 us; speedup vs baseline: 1.2674x; 1.2471x over previous
//
#include <hip/hip_runtime.h>
#include <hip/hip_fp16.h>
#include <cstdint>

#define GRAPHS 128

using half8 = __attribute__((ext_vector_type(8))) _Float16;
using f32x4 = __attribute__((ext_vector_type(4))) float;

__device__ __forceinline__ int lane_bcast_i(int v, int l) {
  return __builtin_amdgcn_readlane(v, l);
}
__device__ __forceinline__ float lane_bcast_f(float v, int l) {
  return __int_as_float(__builtin_amdgcn_readlane(__float_as_int(v), l));
}
__device__ __forceinline__ void load_lds16(const __half* g, __half* l) {
  __builtin_amdgcn_global_load_lds(
      (const __attribute__((address_space(1))) void*)g,
      (__attribute__((address_space(3))) void*)l, 16, 0, 0);
}
#define WAIT_VM0 __builtin_amdgcn_s_waitcnt(0x0F70)  // vmcnt(0) only

// ---------------- weight transpose (histogram path removed entirely) ----------------

__global__ __launch_bounds__(256) void k_wt(
    const float* __restrict__ W1, __half* __restrict__ w1t,
    const float* __restrict__ W2, __half* __restrict__ w2t, int F, int HC, int LH) {
  int id = blockIdx.x * 256 + threadIdx.x;
  if (id < F * HC) {
    int nn = id / F, kk = id % F;
    w1t[(size_t)nn * F + kk] = __float2half(W1[(size_t)kk * HC + nn]);
    return;
  }
  id -= F * HC;
  if (id < HC * LH) {
    int nn = id / HC, kk = id % HC;
    w2t[(size_t)nn * HC + kk] = __float2half(W2[(size_t)kk * LH + nn]);
  }
}

// ---------------- two-pass dst-sort (CSR build) with XCD-friendly writes ----------------
// Buckets = 256-node ranges (dst>>8). All stores land in block-private contiguous
// windows -> lines filled densely by ONE block (one XCD) -> write traffic ~= payload,
// killing the 8x cross-XCD partial-line write amplification measured on k_scatter.

// P0: per-(bucket,block) histogram. grid 256 x 256 threads, grid-stride over edges.
__global__ __launch_bounds__(256) void k_hist(const int* __restrict__ ei, int E, int ET,
                                              int* __restrict__ histT, int NBK) {
  __shared__ int h[256];
  int tid = threadIdx.x, blk = blockIdx.x;
  h[tid] = 0;
  __syncthreads();
  for (int e = blk * 256 + tid; e < ET; e += 256 * 256) {
    int d = (e < E) ? ei[E + e] : (e - E);
    atomicAdd(&h[d >> 8], 1);
  }
  __syncthreads();
  if (tid < NBK) histT[tid * 256 + blk] = h[tid];
}

// per-bucket exclusive scan over the 256 blocks
__global__ __launch_bounds__(256) void k_scan1(const int* __restrict__ histT,
                                               int* __restrict__ bexcl,
                                               int* __restrict__ total) {
  int k = blockIdx.x, tid = threadIdx.x, lane = tid & 63, wid = tid >> 6;
  int v = histT[k * 256 + tid];
  int incl = v;
#pragma unroll
  for (int o = 1; o < 64; o <<= 1) { int u = __shfl_up(incl, o); if (lane >= o) incl += u; }
  __shared__ int ws[4];
  if (lane == 63) ws[wid] = incl;
  __syncthreads();
  int woff = 0;
  for (int w = 0; w < wid; ++w) woff += ws[w];
  incl += woff;
  bexcl[k * 256 + tid] = incl - v;
  if (tid == 255) total[k] = incl;
}

// exclusive scan over bucket totals -> bucket start offsets (+ sentinel)
__global__ __launch_bounds__(256) void k_scan2(const int* __restrict__ total,
                                               int* __restrict__ bstart, int NBK) {
  int tid = threadIdx.x, lane = tid & 63, wid = tid >> 6;
  int v = (tid < NBK) ? total[tid] : 0;
  int incl = v;
#pragma unroll
  for (int o = 1; o < 64; o <<= 1) { int u = __shfl_up(incl, o); if (lane >= o) incl += u; }
  __shared__ int ws[4];
  if (lane == 63) ws[wid] = incl;
  __syncthreads();
  int woff = 0;
  for (int w = 0; w < wid; ++w) woff += ws[w];
  incl += woff;
  bstart[tid] = incl - v;
  if (tid == 255) bstart[256] = incl;
}

// P1: partition edges into bucket-contiguous tmp. Each (block,bucket) run is a private
// contiguous window (avg ~17 int2 = 136B) -> near line-dense stores.
__global__ __launch_bounds__(256) void k_part(const int* __restrict__ ei, int E, int ET,
                                              const int* __restrict__ bexcl,
                                              const int* __restrict__ bstart,
                                              int2* __restrict__ tmp, int NBK) {
  __shared__ int cur[256];
  int tid = threadIdx.x, blk = blockIdx.x;
  if (tid < NBK) cur[tid] = bstart[tid] + bexcl[tid * 256 + blk];
  __syncthreads();
  for (int e = blk * 256 + tid; e < ET; e += 256 * 256) {
    int s, d;
    if (e < E) { s = ei[e]; d = ei[E + e]; } else { s = d = e - E; }
    int pos = atomicAdd(&cur[d >> 8], 1);
    tmp[pos] = make_int2(s, d);
  }
}

// P2: within-bucket dst-sort. One block per bucket; LDS node-histogram + scan gives
// exact global CSR slots (bucket start == rowptr of its first node). Output window
// ~34KB, exclusively owned -> L2-dense, write ~= payload.
__global__ __launch_bounds__(256) void k_scat2(const int2* __restrict__ tmp,
                                               const int* __restrict__ bstart,
                                               int2* __restrict__ epk) {
  int k = blockIdx.x, tid = threadIdx.x, lane = tid & 63, wid = tid >> 6;
  int lo = bstart[k], hi = bstart[k + 1], n0 = k << 8;
  __shared__ int cnt[256];
  cnt[tid] = 0;
  __syncthreads();
  for (int e = lo + tid; e < hi; e += 256) atomicAdd(&cnt[tmp[e].y - n0], 1);
  __syncthreads();
  int v = cnt[tid];
  int incl = v;
#pragma unroll
  for (int o = 1; o < 64; o <<= 1) { int u = __shfl_up(incl, o); if (lane >= o) incl += u; }
  __shared__ int ws[4];
  if (lane == 63) ws[wid] = incl;
  __syncthreads();
  int woff = 0;
  for (int w = 0; w < wid; ++w) woff += ws[w];
  incl += woff;
  __shared__ int cur[256];
  cur[tid] = lo + incl - v;
  __syncthreads();
  for (int e = lo + tid; e < hi; e += 256) {
    int2 sd = tmp[e];
    int pos = atomicAdd(&cur[sd.y - n0], 1);
    epk[pos] = sd;
  }
}

// ---------------- MFMA GEMM, LDS-tiled, fp32 A staged ONCE, NH head-blocks looped -----------
// MODE 0: A = raw fp32 (x).
// MODE 1: A = unnormalized numerators (h1f) -> /denom + bias + ELU during staging.

template <int KT, int ASTR, int NH, int MODE>
__global__ __launch_bounds__(256) void k_gemm_mfma(
    const float* __restrict__ Af, const __half* __restrict__ Bth,
    __half* __restrict__ C, const float* __restrict__ attS, const float* __restrict__ attD,
    float* __restrict__ aS, float* __restrict__ aD, const float* __restrict__ bias,
    const float* __restrict__ dnm, int Ndn, int M, int NC) {
  constexpr int K8 = KT / 8;
  constexpr int KS = KT / 32;
  __shared__ __align__(16) _Float16 Asm[64 * KT];
  __shared__ __align__(16) _Float16 Csm[64 * 64];
  __shared__ float sS[64][4], sD[64][4];
  int tid = threadIdx.x;
  int w = tid >> 6, lane = tid & 63;
  int col = lane & 15, quad = lane >> 4;
  int m0 = blockIdx.x * 64;
  half8* As8 = (half8*)Asm;
  for (int i = tid; i < 64 * K8; i += 256) {
    int row = i / K8, c8 = i % K8;
    int gm = min(m0 + row, M - 1);
    const float* src = Af + (size_t)gm * KT + c8 * 8;
    float4 v0 = *(const float4*)src;
    float4 v1 = *(const float4*)(src + 4);
    float o[8] = {v0.x, v0.y, v0.z, v0.w, v1.x, v1.y, v1.z, v1.w};
    if (MODE == 1) {
      int c = c8 * 8;
      float inv = 1.0f / fmaxf(dnm[(size_t)(c8 >> 3) * Ndn + gm], 1e-16f);
#pragma unroll
      for (int k = 0; k < 8; ++k) {
        float t = o[k] * inv + bias[c + k];
        o[k] = t > 0.f ? t : __expf(t) - 1.f;
      }
    }
    half8 h;
#pragma unroll
    for (int k = 0; k < 8; ++k) h[k] = (_Float16)o[k];
    As8[i] = h;
  }
  __syncthreads();
  const half8* B8 = (const half8*)Bth;
  for (int h = 0; h < NH; ++h) {
    int nblk = h * 64;
    int n0w = nblk + w * 16;
    half8 bf[KS];
#pragma unroll
    for (int s = 0; s < KS; ++s) bf[s] = B8[(size_t)(n0w + col) * K8 + s * 4 + quad];
    float asv = attS[n0w + col], adv = attD[n0w + col];
    if (h) __syncthreads();  // prev head's sS/sD consumed + Csm flushed
    f32x4 accs[4];
#pragma unroll
    for (int i = 0; i < 4; ++i) {
      f32x4 acc = {0.f, 0.f, 0.f, 0.f};
#pragma unroll
      for (int s = 0; s < KS; ++s) {
        half8 a = *(const half8*)&Asm[(i * 16 + col) * KT + s * 32 + quad * 8];
        acc = __builtin_amdgcn_mfma_f32_16x16x32_f16(a, bf[s], acc, 0, 0, 0);
      }
      accs[i] = acc;
#pragma unroll
      for (int r = 0; r < 4; ++r) {
        float sv = acc[r] * asv, dv = acc[r] * adv;
#pragma unroll
        for (int o = 1; o < 16; o <<= 1) { sv += __shfl_xor(sv, o); dv += __shfl_xor(dv, o); }
        if (col == 0) {
          int ml = i * 16 + quad * 4 + r;
          sS[ml][w] = sv; sD[ml][w] = dv;
        }
      }
    }
    __syncthreads();
    if (tid < 64) {
      int m = m0 + tid;
      if (m < M) {
        aS[(size_t)m * ASTR + h] = sS[tid][0] + sS[tid][1] + sS[tid][2] + sS[tid][3];
        aD[(size_t)m * ASTR + h] = sD[tid][0] + sD[tid][1] + sD[tid][2] + sD[tid][3];
      }
    }
#pragma unroll
    for (int i = 0; i < 4; ++i)
#pragma unroll
      for (int r = 0; r < 4; ++r)
        Csm[(i * 16 + quad * 4 + r) * 64 + w * 16 + col] = (_Float16)accs[i][r];
    __syncthreads();
    for (int i = tid; i < 64 * 8; i += 256) {
      int row = i >> 3, c8 = i & 7;
      int gm = m0 + row;
      if (gm < M)
        *(half8*)&C[(size_t)gm * NC + nblk + c8 * 8] = ((half8*)Csm)[row * 8 + c8];
    }
  }
}

// ---------------- edge-parallel aggregation, 64-edge chunks, interior plain stores ----------
// One chunk per wave, single vmcnt(0) covering alpha gathers + 8 staging DMAs.
// A segment with segstart>0 && u<63 is provably the COMPLETE global dst-segment
// (sorted edges) -> plain store over the memset-0 instead of atomicAdd (no L2 RMW).

template <int NH>
__global__ __launch_bounds__(256) void k_aggE(
    const int2* __restrict__ ep,
    const float* __restrict__ aS, const float* __restrict__ aD,
    const __half* __restrict__ xp, float* __restrict__ outf, float* __restrict__ dnm,
    int ET, int rowstr, int ostr, int Ndn) {
  __shared__ __half stage[4][4096];
  int wv = (blockIdx.x * 256 + (int)threadIdx.x) >> 6;
  int lane = threadIdx.x & 63;
  int wid = (threadIdx.x >> 6) & 3;
  __half* st = stage[wid];
  int head = blockIdx.y;
  int coloff = head * 64;
  int e0 = wv * 64;
  if (e0 >= ET) return;
  int j = e0 + lane;
  int jc = min(j, ET - 1);
  int2 sd = ep[jc];                            // coalesced 8B
  int sreg = sd.x, dstv = sd.y;
  // inline alpha: issued before DMAs; same vmcnt(0) covers everything
  float dd = 0.f;
  if (NH == 3) {
    float4 a4 = *(const float4*)&aS[(size_t)sreg * 4];   // random 16B, L2-resident
    float4 b4 = *(const float4*)&aD[(size_t)dstv * 4];   // dst-sorted -> near-coalesced
    float v = (head == 0) ? (a4.x + b4.x) : ((head == 1) ? (a4.y + b4.y) : (a4.z + b4.z));
    v = v > 0.f ? v : 0.2f * v;
    dd = __expf(v);
  } else {
    float v = aS[sreg] + aD[dstv];
    v = v > 0.f ? v : 0.2f * v;
    dd = __expf(v);
  }
  if (j >= ET) dd = 0.f;
#pragma unroll
  for (int k = 0; k < 8; ++k) {
    int src = __shfl(sreg, k * 8 + (lane >> 3));
    const __half* g = xp + (size_t)src * rowstr + coloff + (lane & 7) * 8;
    load_lds16(g, st + k * 512);               // 8 rows of 64 halves per DMA
  }
  int dn = __shfl_down(dstv, 1);
  unsigned long long bmask = __ballot(lane == 63 || dn != dstv);  // segment-end lanes
  WAIT_VM0;                                    // the only wait in the wave's lifetime
  float acc = 0.f, dsum = 0.f;
  int dcur = lane_bcast_i(dstv, 0);
  int segstart = 0;
#pragma unroll 4
  for (int u = 0; u < 64; ++u) {
    float c = lane_bcast_f(dd, u);
    acc = fmaf(c, __half2float(st[(u >> 3) * 512 + (u & 7) * 64 + lane]), acc);
    dsum += c;
    if ((bmask >> u) & 1ull) {                 // wave-uniform scalar test
      size_t op = (size_t)dcur * ostr + coloff + lane;
      if (segstart > 0 && u < 63) {            // complete segment: plain store
        outf[op] = acc;
        if (lane == 0) dnm[(size_t)head * Ndn + dcur] = dsum;
      } else {                                 // chunk-boundary segment: atomic
        atomicAdd(&outf[op], acc);
        if (lane == 0) atomicAdd(&dnm[(size_t)head * Ndn + dcur], dsum);
      }
      acc = 0.f; dsum = 0.f; segstart = u + 1;
      if (u < 63) dcur = lane_bcast_i(dstv, u + 1);
    }
  }
}

// ---------------- fused pooling + final linear (one block per graph, NO atomics) ------------

__global__ __launch_bounds__(256) void k_poolfinal(
    const float* __restrict__ h2f, const float* __restrict__ dnm2,
    const int* __restrict__ batch, const float* __restrict__ b2,
    const float* __restrict__ lw, const float* __restrict__ lb,
    float* __restrict__ out, int N) {
  int g = blockIdx.x;
  __shared__ int sse[2];
  __shared__ float red[4][64];
  if (threadIdx.x < 2) {
    int target = g + (int)threadIdx.x;
    int lo = 0, hi = N;
    while (lo < hi) { int mid = (lo + hi) >> 1; if (batch[mid] < target) lo = mid + 1; else hi = mid; }
    sse[threadIdx.x] = lo;
  }
  __syncthreads();
  int start = sse[0], end = sse[1];
  int lane = threadIdx.x & 63, wid = threadIdx.x >> 6;
  float acc = 0.f;
  for (int n = start + wid; n < end; n += 4) {
    float inv = 1.0f / fmaxf(dnm2[n], 1e-16f);
    acc = fmaf(h2f[(size_t)n * 64 + lane], inv, acc);
  }
  red[wid][lane] = acc;
  __syncthreads();
  if (wid == 0) {
    float inv = 1.0f / fmaxf((float)(end - start), 1.0f);
    float pv = (red[0][lane] + red[1][lane] + red[2][lane] + red[3][lane]) * inv + b2[lane];
#pragma unroll
    for (int k = 0; k < 10; ++k) {
      float v = pv * lw[lane * 10 + k];
#pragma unroll
      for (int o = 1; o < 64; o <<= 1) v += __shfl_xor(v, o);
      if (lane == 0) out[g * 10 + k] = v + lb[k];
    }
  }
}

extern "C" void kernel_launch(void* const* d_in, const int* in_sizes, int n_in,
                              void* d_out, int out_size, void* d_ws, size_t ws_size,
                              hipStream_t stream) {
  const float* x = (const float*)d_in[0];
  const int* ei = (const int*)d_in[1];
  const int* batch = (const int*)d_in[2];
  const float* W1 = (const float*)d_in[3];
  const float* as1 = (const float*)d_in[4];
  const float* ad1 = (const float*)d_in[5];
  const float* b1 = (const float*)d_in[6];
  const float* W2 = (const float*)d_in[7];
  const float* as2 = (const float*)d_in[8];
  const float* ad2 = (const float*)d_in[9];
  const float* b2 = (const float*)d_in[10];
  const float* lw = (const float*)d_in[11];
  const float* lb = (const float*)d_in[12];
  float* out = (float*)d_out;

  const int N = in_sizes[2];        // 50000
  const int E = in_sizes[1] / 2;    // 800000
  const int ET = E + N;             // + self loops
  const int F = in_sizes[0] / N;    // 128
  const int HC = in_sizes[6];       // 192
  const int LH = in_sizes[10];      // 64
  const int NBK = (N + 255) >> 8;   // 196 node-buckets (<=256 required)

  size_t off = 0;
  auto alo = [&](size_t bytes) -> char* {
    char* p = (char*)d_ws + off;
    off += (bytes + 255) & ~(size_t)255;
    return p;
  };
  float* h1f = (float*)alo((size_t)N * 192 * 4);    // fp32 unnormalized numerators
  float* h2f = (float*)alo((size_t)N * 64 * 4);
  float* dnm1 = (float*)alo((size_t)3 * N * 4);     // softmax denominators [head][node]
  float* dnm2 = (float*)alo((size_t)N * 4);
  size_t zbytes = off;                              // zero everything above
  float* aS1 = (float*)alo((size_t)N * 4 * 4);      // direct-stored by GEMM
  float* aD1 = (float*)alo((size_t)N * 4 * 4);
  float* aS2 = (float*)alo((size_t)N * 4);
  float* aD2 = (float*)alo((size_t)N * 4);
  int* histT = (int*)alo((size_t)256 * 256 * 4);
  int* bexcl = (int*)alo((size_t)256 * 256 * 4);
  int* total = (int*)alo((size_t)256 * 4);
  int* bstart = (int*)alo((size_t)257 * 4);
  int2* tmp = (int2*)alo((size_t)ET * 8);           // bucket-partitioned edges
  int2* epk = (int2*)alo((size_t)ET * 8);           // final dst-sorted (src,dst)
  __half* w1t = (__half*)alo((size_t)HC * F * 2);
  __half* w2t = (__half*)alo((size_t)LH * HC * 2);
  __half* xp1 = (__half*)alo((size_t)N * 192 * 2 + 512);  // +pad: DMA clamp overreach
  __half* xp2 = (__half*)alo((size_t)N * 64 * 2 + 512);

  hipMemsetAsync(d_ws, 0, zbytes, stream);
  int wtTot = F * HC + HC * LH;
  int wtb = (wtTot + 255) / 256;
  k_wt<<<wtb, 256, 0, stream>>>(W1, w1t, W2, w2t, F, HC, LH);
  // ---- CSR build: histogram -> 2-level scan -> partition -> in-bucket sort ----
  k_hist<<<256, 256, 0, stream>>>(ei, E, ET, histT, NBK);
  k_scan1<<<NBK, 256, 0, stream>>>(histT, bexcl, total);
  k_scan2<<<1, 256, 0, stream>>>(total, bstart, NBK);
  k_part<<<256, 256, 0, stream>>>(ei, E, ET, bexcl, bstart, tmp, NBK);
  k_scat2<<<NBK, 256, 0, stream>>>(tmp, bstart, epk);

  int mb = (N + 63) / 64;
  int wavesE = (ET + 63) / 64;
  int ebk = (wavesE + 3) / 4;

  // ---- layer 1: MFMA GEMM (A staged once, 3 head-blocks looped) -> edge-parallel agg ----
  k_gemm_mfma<128, 4, 3, 0><<<mb, 256, 0, stream>>>(x, w1t, xp1, as1, ad1, aS1, aD1,
                                                    nullptr, nullptr, 0, N, HC);
  dim3 ge1(ebk, 3);
  k_aggE<3><<<ge1, 256, 0, stream>>>(epk, aS1, aD1, xp1, h1f, dnm1,
                                     ET, 192, 192, N);
  // ---- layer 2: MFMA GEMM (A = h1f/denom + bias + ELU) -> agg -> pool+final ----
  k_gemm_mfma<192, 1, 1, 1><<<mb, 256, 0, stream>>>(h1f, w2t, xp2, as2, ad2, aS2, aD2,
                                                    b1, dnm1, N, N, LH);
  dim3 ge2(ebk, 1);
  k_aggE<1><<<ge2, 256, 0, stream>>>(epk, aS2, aD2, xp2, h2f, dnm2,
                                     ET, 64, 64, N);
  k_poolfinal<<<GRAPHS, 256, 0, stream>>>(h2f, dnm2, batch, b2, lw, lb, out, N);
}